// Round 12
// baseline (544.243 us; speedup 1.0000x reference)
//
#include <hip/hip_runtime.h>
#include <math.h>

#define NP 8192
#define RSTR 264  // bf16 elems per LDS tile row: 528B, 16B-aligned, bank-stride 4 -> 2-way (free)

using f32x4  = __attribute__((ext_vector_type(4))) float;
using bf16x4 = __attribute__((ext_vector_type(4))) short;
using bf16x8 = __attribute__((ext_vector_type(8))) short;

__device__ __forceinline__ unsigned short f2bf(float x) {
  unsigned int u = __float_as_uint(x);
  u = (u + 0x7FFFu + ((u >> 16) & 1u)) >> 16;
  return (unsigned short)u;
}
__device__ __forceinline__ float fast_log2(float x) { float r; asm("v_log_f32 %0, %1" : "=v"(r) : "v"(x)); return r; }
__device__ __forceinline__ float fast_exp2(float x) { float r; asm("v_exp_f32 %0, %1" : "=v"(r) : "v"(x)); return r; }
__device__ __forceinline__ float fast_rcp(float x)  { float r; asm("v_rcp_f32 %0, %1" : "=v"(r) : "v"(x)); return r; }
__device__ __forceinline__ float siluf(float x) { return x / (1.0f + expf(-x)); }
__device__ __forceinline__ float softplusf(float x) { return (x > 20.0f) ? x : log1pf(expf(x)); }
__device__ __forceinline__ float dot4(const float4 a, const float4 b) {
  return a.x * b.x + a.y * b.y + a.z * b.z + a.w * b.w;
}

// ws layout (bytes):
//   [36864,+32KB)  a[8192] f32   (a_j = 2*log2e*lw_j)
//   [73728,+1MB)   Bt2: bf16, fragment-native layout
//                  element (c,j): idx = (((j>>5)*4 + (c>>4))*64 + ((j>>3)&3)*16 + (c&15))*8 + (j&7)

// ---------------- kernel 1: fused setup + per-particle transition + loglik ----
__global__ __launch_bounds__(128) void k_particle(
    const float* __restrict__ rh,   const float* __restrict__ rlo,
    const float* __restrict__ z,    const float* __restrict__ rlog,
    const float* __restrict__ logw, const float* __restrict__ h_t,
    const float* __restrict__ obs_p,
    const float* __restrict__ eps_h, const float* __restrict__ eps_l,
    const float* __restrict__ embed,
    const float* __restrict__ W_rt1, const float* __restrict__ b_rt1,
    const float* __restrict__ W_rt2, const float* __restrict__ b_rt2,
    const float* __restrict__ W_d1,  const float* __restrict__ b_d1,
    const float* __restrict__ W_d2,  const float* __restrict__ b_d2,
    const float* __restrict__ W_d3,  const float* __restrict__ b_d3,
    const float* __restrict__ W_g,   const float* __restrict__ b_g,
    const float* __restrict__ W_c,   const float* __restrict__ b_c,
    const float* __restrict__ log_R, const float* __restrict__ log_obs_scale,
    const float* __restrict__ W_a1,  const float* __restrict__ b_a1,
    const float* __restrict__ W_a2,  const float* __restrict__ b_a2,
    float* __restrict__ a_out, unsigned short* __restrict__ Bt) {
  __shared__ float d1c[64 * 48];
  __shared__ float gcs[32 * 48];
  __shared__ float ccs[32 * 48];
  __shared__ float rt1c[32 * 16];
  __shared__ float d2s[32 * 64];
  __shared__ float d3s[4 * 32];
  __shared__ float rt2s[5 * 32];
  __shared__ float embs[80];
  __shared__ float cD1[64], cRT1[32], cG[32], cC[32];
  __shared__ float bD2[32], bD3[4], bRT2[8];
  __shared__ float a1s[16], scal[8];
  __shared__ float x1ex[32 * 68];
  __shared__ float tx[32 * 36];
  __shared__ float stex[32 * 52];

  const int t = threadIdx.x;

#define STAGEM(DST, SRC, ROWS, SSTR, C0, NC)                          \
  for (int e = t; e < (ROWS) * (NC); e += 128) {                      \
    const int ro = e / (NC);                                          \
    const int co = e - ro * (NC);                                     \
    DST[e] = SRC[ro * (SSTR) + (C0) + co];                            \
  }
  STAGEM(d1c, W_d1, 64, 112, 64, 48)
  STAGEM(gcs, W_g, 32, 112, 64, 48)
  STAGEM(ccs, W_c, 32, 112, 64, 48)
  STAGEM(rt1c, W_rt1, 32, 80, 64, 16)
#undef STAGEM
  for (int e = t; e < 2048; e += 128) d2s[e] = W_d2[e];
  if (t < 128) d3s[t] = W_d3[t];
  for (int e = t; e < 160; e += 128) rt2s[e] = W_rt2[e];
  if (t < 80) embs[t] = embed[t];
  if (t < 32) bD2[t] = b_d2[t];
  if (t < 4)  bD3[t] = b_d3[t];
  if (t < 5)  bRT2[t] = b_rt2[t];

  for (int o = t; o < 160; o += 128) {
    const float* wr; float bb;
    if (o < 64)       { wr = W_d1 + o * 112;        bb = b_d1[o]; }
    else if (o < 96)  { wr = W_rt1 + (o - 64) * 80; bb = b_rt1[o - 64]; }
    else if (o < 128) { wr = W_g + (o - 96) * 112;  bb = b_g[o - 96]; }
    else              { wr = W_c + (o - 128) * 112; bb = b_c[o - 128]; }
    float acc = bb;
    #pragma unroll
    for (int m = 0; m < 64; m += 4)
      acc += dot4(*(const float4*)(wr + m), *(const float4*)(h_t + m));
    if (o < 64) cD1[o] = acc;
    else if (o < 96) cRT1[o - 64] = acc;
    else if (o < 128) cG[o - 96] = acc;
    else cC[o - 128] = acc;
  }
  if (t < 16) {
    float acc = b_a1[t];
    #pragma unroll
    for (int m = 0; m < 64; m += 4)
      acc += dot4(*(const float4*)(W_a1 + t * 64 + m), *(const float4*)(h_t + m));
    a1s[t] = siluf(acc);
  } else if (t == 16) {
    scal[1] = fminf(fmaxf(expf(log_R[0]), 0.15f), 2.5f);
  } else if (t >= 17 && t < 22) {
    scal[2 + t - 17] = softplusf(log_obs_scale[t - 17]);
  }
  __syncthreads();  // B0
  if (t == 0) {
    float acc = b_a2[0];
    #pragma unroll
    for (int k = 0; k < 16; ++k) acc += W_a2[k] * a1s[k];
    scal[0] = acc;
  }

  const int l = t & 63, lbase = l & ~3;
  const int q = t >> 2, s = t & 3;
  const int j = blockIdx.x * 32 + q;
  const float obs = obs_p[0];

  float rlj[15];
  #pragma unroll
  for (int k = 0; k < 15; ++k) rlj[k] = rlog[j * 15 + k];
  float m0 = rlj[0];
  #pragma unroll
  for (int k = 1; k < 15; ++k) m0 = fmaxf(m0, rlj[k]);
  float sum = 0.0f, e5[5];
  #pragma unroll
  for (int k = 0; k < 15; ++k) { float e = expf(rlj[k] - m0); if (k < 5) e5[k] = e; sum += e; }
  const float inv = 1.0f / sum;

  float remb[16];
  #pragma unroll
  for (int c = 0; c < 16; ++c) {
    float acc = e5[0] * embs[c];
    #pragma unroll
    for (int k = 1; k < 5; ++k) acc += e5[k] * embs[k * 16 + c];
    remb[c] = acc * inv;
  }

  float zj[32];
  #pragma unroll
  for (int c = 0; c < 32; c += 4) {
    const float4 v = *(const float4*)(z + j * 32 + c);
    zj[c] = v.x; zj[c + 1] = v.y; zj[c + 2] = v.z; zj[c + 3] = v.w;
  }

  #pragma unroll
  for (int r = 0; r < 8; ++r) {
    const int o = 4 * r + s;
    float acc = cRT1[o];
    #pragma unroll
    for (int c = 0; c < 16; ++c) acc += rt1c[o * 16 + c] * remb[c];
    tx[q * 36 + o] = siluf(acc);
  }
  __syncthreads();  // B1
  float t1[32];
  #pragma unroll
  for (int c = 0; c < 32; c += 4) {
    const float4 v = *(const float4*)(tx + q * 36 + c);
    t1[c] = v.x; t1[c + 1] = v.y; t1[c + 2] = v.z; t1[c + 3] = v.w;
  }
  float updS = bRT2[s], upd4 = bRT2[4];
  #pragma unroll
  for (int c = 0; c < 32; ++c) { updS += rt2s[s * 32 + c] * t1[c]; upd4 += rt2s[128 + c] * t1[c]; }
  float nlg[15];
  #pragma unroll
  for (int k = 0; k < 4; ++k) nlg[k] = 0.7f * rlj[k] + 0.3f * __shfl(updS, lbase + k);
  nlg[4] = 0.7f * rlj[4] + 0.3f * upd4;
  #pragma unroll
  for (int k = 5; k < 15; ++k) nlg[k] = rlj[k];

  #pragma unroll
  for (int r = 0; r < 16; ++r) {
    const int o = 4 * r + s;
    const float* wrow = d1c + o * 48;
    float acc = cD1[o];
    #pragma unroll
    for (int c = 0; c < 16; ++c) acc += wrow[c] * remb[c];
    #pragma unroll
    for (int c = 0; c < 32; ++c) acc += wrow[16 + c] * zj[c];
    x1ex[q * 68 + o] = siluf(acc);
  }
  __syncthreads();  // B2

  float acc8[8];
  #pragma unroll
  for (int r = 0; r < 8; ++r) acc8[r] = bD2[4 * r + s];
  #pragma unroll
  for (int half = 0; half < 2; ++half) {
    float xh[32];
    #pragma unroll
    for (int c = 0; c < 32; c += 4) {
      const float4 v = *(const float4*)(x1ex + q * 68 + half * 32 + c);
      xh[c] = v.x; xh[c + 1] = v.y; xh[c + 2] = v.z; xh[c + 3] = v.w;
    }
    #pragma unroll
    for (int r = 0; r < 8; ++r) {
      const int o = 4 * r + s;
      #pragma unroll
      for (int c = 0; c < 32; ++c) acc8[r] += d2s[o * 64 + half * 32 + c] * xh[c];
    }
  }
  #pragma unroll
  for (int r = 0; r < 8; ++r) tx[q * 36 + 4 * r + s] = siluf(acc8[r]);
  __syncthreads();  // B3
  float x2v[32];
  #pragma unroll
  for (int c = 0; c < 32; c += 4) {
    const float4 v = *(const float4*)(tx + q * 36 + c);
    x2v[c] = v.x; x2v[c + 1] = v.y; x2v[c + 2] = v.z; x2v[c + 3] = v.w;
  }
  float dps = bD3[s];
  #pragma unroll
  for (int c = 0; c < 32; ++c) dps += d3s[s * 32 + c] * x2v[c];
  const float dp0 = __shfl(dps, lbase), dp1 = __shfl(dps, lbase + 1);
  const float dp2 = __shfl(dps, lbase + 2), dp3 = __shfl(dps, lbase + 3);
  const float sig_h = softplusf(dp2) + 0.01f;
  const float sig_l = softplusf(dp3) + 0.01f;
  const float nh = fmaxf(rh[j] + dp0 + sig_h * eps_h[j], 0.0f);
  const float nl = fmaxf(rlo[j] + dp1 + sig_l * eps_l[j], 0.0f);

  #pragma unroll
  for (int r = 0; r < 8; ++r) {
    const int o = 4 * r + s;
    const float* gr = gcs + o * 48;
    const float* cr = ccs + o * 48;
    float ga = cG[o], caa = cC[o];
    #pragma unroll
    for (int c = 0; c < 16; ++c) { ga += gr[c] * remb[c]; caa += cr[c] * remb[c]; }
    #pragma unroll
    for (int c = 0; c < 32; ++c) { ga += gr[16 + c] * zj[c]; caa += cr[16 + c] * zj[c]; }
    const float gs = 1.0f / (1.0f + expf(-ga));
    stex[q * 52 + 2 + o] = gs * zj[o] + (1.0f - gs) * tanhf(caa);
  }

  if (s == 0) {
    stex[q * 52 + 0] = nh;
    stex[q * 52 + 1] = nl;
    #pragma unroll
    for (int k = 0; k < 15; ++k) stex[q * 52 + 34 + k] = nlg[k];
    float m1 = nlg[0];
    #pragma unroll
    for (int k = 1; k < 15; ++k) m1 = fmaxf(m1, nlg[k]);
    float sum1 = 0.0f, e5b[5];
    #pragma unroll
    for (int k = 0; k < 15; ++k) { float e = expf(nlg[k] - m1); if (k < 5) e5b[k] = e; sum1 += e; }
    float dot = 0.0f;
    #pragma unroll
    for (int k = 0; k < 5; ++k) dot += e5b[k] * scal[2 + k];
    dot /= sum1;
    const float R  = fminf(fmaxf(scal[1] * dot, 0.15f), 4.0f);
    const float zz = (obs - nh) / R;
    const float xx = scal[0] * zz;
    float lcdf;
    if (xx > -6.0f) {
      double p = 0.5 * erfc(-(double)xx * 0.7071067811865475244);
      lcdf = (float)log(p);
    } else {
      const float ix2 = 1.0f / (xx * xx);
      const float ser = 1.0f + ix2 * (-1.0f + ix2 * (3.0f + ix2 * (-15.0f + ix2 * 105.0f)));
      lcdf = -0.5f * xx * xx - logf(-xx) - 0.918938533f + logf(ser);
    }
    const float loglik = 0.693147181f - logf(R) - 0.918938533f - 0.5f * zz * zz + lcdf;
    a_out[j] = (logw[j] + loglik) * 2.8853900817779268f;  // (1/tau)*log2(e)
  }
  __syncthreads();  // B4

  // Bt2 write: thread c owns state-row c; fragment-native layout, 16B stores.
  if (t < 64) {
    const int c = t;
    const int b = c >> 4, rowc = c & 15;
    if (c < 49) {
      #pragma unroll
      for (int m = 0; m < 4; ++m) {
        bf16x8 v8;
        #pragma unroll
        for (int r = 0; r < 8; ++r) v8[r] = (short)f2bf(stex[(8 * m + r) * 52 + c]);
        *(bf16x8*)(Bt + (size_t)(((blockIdx.x * 4 + b) * 64) + m * 16 + rowc) * 8) = v8;
      }
    } else if (c == 49) {
      bf16x8 v8;
      #pragma unroll
      for (int r = 0; r < 8; ++r) v8[r] = (short)0x3F80;
      #pragma unroll
      for (int m = 0; m < 4; ++m)
        *(bf16x8*)(Bt + (size_t)(((blockIdx.x * 4 + b) * 64) + m * 16 + rowc) * 8) = v8;
    } else {
      bf16x8 v8;
      #pragma unroll
      for (int r = 0; r < 8; ++r) v8[r] = 0;
      #pragma unroll
      for (int m = 0; m < 4; ++m)
        *(bf16x8*)(Bt + (size_t)(((blockIdx.x * 4 + b) * 64) + m * 16 + rowc) * 8) = v8;
    }
  }
}

// ---------------- kernel 2: fused gumbel-softmax @ state (MFMA, pipelined) ----
// 8 waves/block, wave-private tiles, 256-col groups, 2-stage register pipeline.
struct UTile { float4 v[16]; };

__device__ __forceinline__ void load_group(UTile& ut, float4& av,
                                           const float* __restrict__ u,
                                           const float* __restrict__ a,
                                           int i0, int cb, int lc4) {
  #pragma unroll
  for (int r = 0; r < 16; ++r)
    ut.v[r] = *(const float4*)(u + (size_t)(i0 + r) * NP + cb + lc4);
  av = *(const float4*)(a + cb + lc4);
}

__device__ __forceinline__ void transform_store(const UTile& ut, const float4 av,
                                                unsigned short* __restrict__ Wwave, int lc4) {
  const float e2a0 = fast_exp2(av.x), e2a1 = fast_exp2(av.y);
  const float e2a2 = fast_exp2(av.z), e2a3 = fast_exp2(av.w);
  #pragma unroll
  for (int r = 0; r < 16; ++r) {
    bf16x4 o;
    const float xs0 = ut.v[r].x, xs1 = ut.v[r].y, xs2 = ut.v[r].z, xs3 = ut.v[r].w;
    // w = exp2(a)/X^2, X = -ln(u+1e-10)+1e-10  (rcp ~1ulp, invisible at bf16)
    {
      const float X = fmaf(fast_log2(xs0 + 1e-10f), -0.69314718056f, 1e-10f);
      const float rr = fast_rcp(X);
      o[0] = (short)f2bf(e2a0 * rr * rr);
    }
    {
      const float X = fmaf(fast_log2(xs1 + 1e-10f), -0.69314718056f, 1e-10f);
      const float rr = fast_rcp(X);
      o[1] = (short)f2bf(e2a1 * rr * rr);
    }
    {
      const float X = fmaf(fast_log2(xs2 + 1e-10f), -0.69314718056f, 1e-10f);
      const float rr = fast_rcp(X);
      o[2] = (short)f2bf(e2a2 * rr * rr);
    }
    {
      const float X = fmaf(fast_log2(xs3 + 1e-10f), -0.69314718056f, 1e-10f);
      const float rr = fast_rcp(X);
      o[3] = (short)f2bf(e2a3 * rr * rr);
    }
    *(bf16x4*)(Wwave + r * RSTR + lc4) = o;
  }
}

__global__ __launch_bounds__(512) void k_resample(const float* __restrict__ u,
                                                  const float* __restrict__ a,
                                                  const unsigned short* __restrict__ Bt,
                                                  float* __restrict__ out) {
  // union: wave tiles (8 x 16 x RSTR bf16 = 67584B) during K-loop, cacc (32KB) after
  __shared__ __align__(16) char smem[8 * 16 * RSTR * 2];
  __shared__ float zrow[16];
  const int t = threadIdx.x;
  const int w = t >> 6, l = t & 63;
  const int i0 = blockIdx.x << 4;
  const int jw = w << 10;
  const int lc4 = l << 2;          // col granule within 256-group
  unsigned short* Wwave = (unsigned short*)smem + w * 16 * RSTR;

  f32x4 acc0 = {0.f, 0.f, 0.f, 0.f}, acc1 = acc0, acc2 = acc0, acc3 = acc0;

  UTile tA, tB; float4 aA, aB;
  load_group(tA, aA, u, a, i0, jw, lc4);

  #pragma unroll
  for (int g = 0; g < 4; ++g) {
    const int cb = jw + (g << 8);
    if (g < 3) {
      if (g & 1) load_group(tA, aA, u, a, i0, cb + 256, lc4);   // prefetch g+1
      else       load_group(tB, aB, u, a, i0, cb + 256, lc4);
    }
    if (g & 1) transform_store(tB, aB, Wwave, lc4);             // consume g
    else       transform_store(tA, aA, Wwave, lc4);
    // DS ops are in-order per wave: ds_write(g) naturally follows ds_read(g-1)
    #pragma unroll
    for (int kbl = 0; kbl < 8; ++kbl) {
      const bf16x8 af = *(const bf16x8*)(Wwave + (l & 15) * RSTR + (kbl << 5) + ((l >> 4) << 3));
      const int jblk = (jw >> 5) + (g << 3) + kbl;
      const unsigned short* bp = Bt + (size_t)(jblk << 2) * 512;
      const bf16x8 b0 = *(const bf16x8*)(bp + (0 * 64 + l) * 8);
      const bf16x8 b1 = *(const bf16x8*)(bp + (1 * 64 + l) * 8);
      const bf16x8 b2 = *(const bf16x8*)(bp + (2 * 64 + l) * 8);
      const bf16x8 b3 = *(const bf16x8*)(bp + (3 * 64 + l) * 8);
      acc0 = __builtin_amdgcn_mfma_f32_16x16x32_bf16(af, b0, acc0, 0, 0, 0);
      acc1 = __builtin_amdgcn_mfma_f32_16x16x32_bf16(af, b1, acc1, 0, 0, 0);
      acc2 = __builtin_amdgcn_mfma_f32_16x16x32_bf16(af, b2, acc2, 0, 0, 0);
      acc3 = __builtin_amdgcn_mfma_f32_16x16x32_bf16(af, b3, acc3, 0, 0, 0);
    }
  }

  __syncthreads();                 // all waves done with tiles -> reuse as cacc
  float* cacc = (float*)smem;      // [8][64][16]
  float* crow = cacc + (w * 64 + l) * 16;
  #pragma unroll
  for (int r = 0; r < 4; ++r) {
    crow[0 * 4 + r] = acc0[r];
    crow[1 * 4 + r] = acc1[r];
    crow[2 * 4 + r] = acc2[r];
    crow[3 * 4 + r] = acc3[r];
  }
  __syncthreads();

  // reduce 8 K-chunks; thread t -> col c = t&63, rows ((t>>6)*2 + rr)
  const int c = t & 63;
  float v[2];
  #pragma unroll
  for (int rr = 0; rr < 2; ++rr) {
    const int r    = ((t >> 6) << 1) + rr;
    const int lsrc = ((r >> 2) << 4) | (c & 15);
    const int reg  = ((c >> 4) << 2) + (r & 3);
    float sv = 0.0f;
    #pragma unroll
    for (int ww = 0; ww < 8; ++ww) sv += cacc[(ww * 64 + lsrc) * 16 + reg];
    v[rr] = sv;
    if (c == 49) zrow[r] = sv;  // ones-column = row normalizer Z_i
  }
  __syncthreads();
  if (c < 49) {
    #pragma unroll
    for (int rr = 0; rr < 2; ++rr) {
      const int r = ((t >> 6) << 1) + rr;
      out[(size_t)(i0 + r) * 49 + c] = v[rr] / zrow[r];
    }
  }
}

extern "C" void kernel_launch(void* const* d_in, const int* in_sizes, int n_in,
                              void* d_out, int out_size, void* d_ws, size_t ws_size,
                              hipStream_t stream) {
  const float* rh    = (const float*)d_in[0];
  const float* rlo   = (const float*)d_in[1];
  const float* z     = (const float*)d_in[2];
  const float* rlog  = (const float*)d_in[3];
  const float* logw  = (const float*)d_in[4];
  const float* h_t   = (const float*)d_in[5];
  const float* obs   = (const float*)d_in[6];
  const float* eps_h = (const float*)d_in[7];
  const float* eps_l = (const float*)d_in[8];
  const float* u     = (const float*)d_in[9];
  const float* embed = (const float*)d_in[10];
  const float* W_rt1 = (const float*)d_in[11];
  const float* b_rt1 = (const float*)d_in[12];
  const float* W_rt2 = (const float*)d_in[13];
  const float* b_rt2 = (const float*)d_in[14];
  const float* W_d1  = (const float*)d_in[15];
  const float* b_d1  = (const float*)d_in[16];
  const float* W_d2  = (const float*)d_in[17];
  const float* b_d2  = (const float*)d_in[18];
  const float* W_d3  = (const float*)d_in[19];
  const float* b_d3  = (const float*)d_in[20];
  const float* W_g   = (const float*)d_in[21];
  const float* b_g   = (const float*)d_in[22];
  const float* W_c   = (const float*)d_in[23];
  const float* b_c   = (const float*)d_in[24];
  const float* log_R = (const float*)d_in[25];
  const float* log_obs_scale = (const float*)d_in[26];
  const float* W_a1  = (const float*)d_in[27];
  const float* b_a1  = (const float*)d_in[28];
  const float* W_a2  = (const float*)d_in[29];
  const float* b_a2  = (const float*)d_in[30];

  float* ws_a = (float*)((char*)d_ws + 36864);
  unsigned short* ws_bt = (unsigned short*)((char*)d_ws + 73728);

  k_particle<<<256, 128, 0, stream>>>(rh, rlo, z, rlog, logw, h_t, obs, eps_h, eps_l,
                                      embed, W_rt1, b_rt1, W_rt2, b_rt2,
                                      W_d1, b_d1, W_d2, b_d2, W_d3, b_d3,
                                      W_g, b_g, W_c, b_c, log_R, log_obs_scale,
                                      W_a1, b_a1, W_a2, b_a2, ws_a, ws_bt);
  k_resample<<<512, 512, 0, stream>>>(u, ws_a, ws_bt, (float*)d_out);
}

// Round 13
// 477.930 us; speedup vs baseline: 1.1388x; 1.1388x over previous
//
#include <hip/hip_runtime.h>
#include <math.h>

#define NP 8192
#define TSTR 72              // bf16 per tile row (64 + 8 pad -> 2-way banks, 16B-aligned rows)
#define TILE_ELE (16 * TSTR) // 1152 bf16 = 2304 B per tile

using f32x4  = __attribute__((ext_vector_type(4))) float;
using bf16x4 = __attribute__((ext_vector_type(4))) short;
using bf16x8 = __attribute__((ext_vector_type(8))) short;

__device__ __forceinline__ unsigned short f2bf(float x) {
  unsigned int u = __float_as_uint(x);
  u = (u + 0x7FFFu + ((u >> 16) & 1u)) >> 16;
  return (unsigned short)u;
}
__device__ __forceinline__ float fast_log2(float x) { float r; asm("v_log_f32 %0, %1" : "=v"(r) : "v"(x)); return r; }
__device__ __forceinline__ float fast_exp2(float x) { float r; asm("v_exp_f32 %0, %1" : "=v"(r) : "v"(x)); return r; }
__device__ __forceinline__ float fast_rcp(float x)  { float r; asm("v_rcp_f32 %0, %1" : "=v"(r) : "v"(x)); return r; }
__device__ __forceinline__ float siluf(float x) { return x / (1.0f + expf(-x)); }
__device__ __forceinline__ float softplusf(float x) { return (x > 20.0f) ? x : log1pf(expf(x)); }
__device__ __forceinline__ float dot4(const float4 a, const float4 b) {
  return a.x * b.x + a.y * b.y + a.z * b.z + a.w * b.w;
}

// ws layout (bytes):
//   [36864,+32KB)  a[8192] f32   (a_j = 2*log2e*lw_j)
//   [73728,+1MB)   Bt2: bf16, fragment-native layout
//                  element (c,j): idx = (((j>>5)*4 + (c>>4))*64 + ((j>>3)&3)*16 + (c&15))*8 + (j&7)

// ---------------- kernel 1: fused setup + per-particle transition + loglik ----
__global__ __launch_bounds__(128) void k_particle(
    const float* __restrict__ rh,   const float* __restrict__ rlo,
    const float* __restrict__ z,    const float* __restrict__ rlog,
    const float* __restrict__ logw, const float* __restrict__ h_t,
    const float* __restrict__ obs_p,
    const float* __restrict__ eps_h, const float* __restrict__ eps_l,
    const float* __restrict__ embed,
    const float* __restrict__ W_rt1, const float* __restrict__ b_rt1,
    const float* __restrict__ W_rt2, const float* __restrict__ b_rt2,
    const float* __restrict__ W_d1,  const float* __restrict__ b_d1,
    const float* __restrict__ W_d2,  const float* __restrict__ b_d2,
    const float* __restrict__ W_d3,  const float* __restrict__ b_d3,
    const float* __restrict__ W_g,   const float* __restrict__ b_g,
    const float* __restrict__ W_c,   const float* __restrict__ b_c,
    const float* __restrict__ log_R, const float* __restrict__ log_obs_scale,
    const float* __restrict__ W_a1,  const float* __restrict__ b_a1,
    const float* __restrict__ W_a2,  const float* __restrict__ b_a2,
    float* __restrict__ a_out, unsigned short* __restrict__ Bt) {
  __shared__ float d1c[64 * 48];
  __shared__ float gcs[32 * 48];
  __shared__ float ccs[32 * 48];
  __shared__ float rt1c[32 * 16];
  __shared__ float d2s[32 * 64];
  __shared__ float d3s[4 * 32];
  __shared__ float rt2s[5 * 32];
  __shared__ float embs[80];
  __shared__ float cD1[64], cRT1[32], cG[32], cC[32];
  __shared__ float bD2[32], bD3[4], bRT2[8];
  __shared__ float a1s[16], scal[8];
  __shared__ float x1ex[32 * 68];
  __shared__ float tx[32 * 36];
  __shared__ float stex[32 * 52];

  const int t = threadIdx.x;

#define STAGEM(DST, SRC, ROWS, SSTR, C0, NC)                          \
  for (int e = t; e < (ROWS) * (NC); e += 128) {                      \
    const int ro = e / (NC);                                          \
    const int co = e - ro * (NC);                                     \
    DST[e] = SRC[ro * (SSTR) + (C0) + co];                            \
  }
  STAGEM(d1c, W_d1, 64, 112, 64, 48)
  STAGEM(gcs, W_g, 32, 112, 64, 48)
  STAGEM(ccs, W_c, 32, 112, 64, 48)
  STAGEM(rt1c, W_rt1, 32, 80, 64, 16)
#undef STAGEM
  for (int e = t; e < 2048; e += 128) d2s[e] = W_d2[e];
  if (t < 128) d3s[t] = W_d3[t];
  for (int e = t; e < 160; e += 128) rt2s[e] = W_rt2[e];
  if (t < 80) embs[t] = embed[t];
  if (t < 32) bD2[t] = b_d2[t];
  if (t < 4)  bD3[t] = b_d3[t];
  if (t < 5)  bRT2[t] = b_rt2[t];

  for (int o = t; o < 160; o += 128) {
    const float* wr; float bb;
    if (o < 64)       { wr = W_d1 + o * 112;        bb = b_d1[o]; }
    else if (o < 96)  { wr = W_rt1 + (o - 64) * 80; bb = b_rt1[o - 64]; }
    else if (o < 128) { wr = W_g + (o - 96) * 112;  bb = b_g[o - 96]; }
    else              { wr = W_c + (o - 128) * 112; bb = b_c[o - 128]; }
    float acc = bb;
    #pragma unroll
    for (int m = 0; m < 64; m += 4)
      acc += dot4(*(const float4*)(wr + m), *(const float4*)(h_t + m));
    if (o < 64) cD1[o] = acc;
    else if (o < 96) cRT1[o - 64] = acc;
    else if (o < 128) cG[o - 96] = acc;
    else cC[o - 128] = acc;
  }
  if (t < 16) {
    float acc = b_a1[t];
    #pragma unroll
    for (int m = 0; m < 64; m += 4)
      acc += dot4(*(const float4*)(W_a1 + t * 64 + m), *(const float4*)(h_t + m));
    a1s[t] = siluf(acc);
  } else if (t == 16) {
    scal[1] = fminf(fmaxf(expf(log_R[0]), 0.15f), 2.5f);
  } else if (t >= 17 && t < 22) {
    scal[2 + t - 17] = softplusf(log_obs_scale[t - 17]);
  }
  __syncthreads();  // B0
  if (t == 0) {
    float acc = b_a2[0];
    #pragma unroll
    for (int k = 0; k < 16; ++k) acc += W_a2[k] * a1s[k];
    scal[0] = acc;
  }

  const int l = t & 63, lbase = l & ~3;
  const int q = t >> 2, s = t & 3;
  const int j = blockIdx.x * 32 + q;
  const float obs = obs_p[0];

  float rlj[15];
  #pragma unroll
  for (int k = 0; k < 15; ++k) rlj[k] = rlog[j * 15 + k];
  float m0 = rlj[0];
  #pragma unroll
  for (int k = 1; k < 15; ++k) m0 = fmaxf(m0, rlj[k]);
  float sum = 0.0f, e5[5];
  #pragma unroll
  for (int k = 0; k < 15; ++k) { float e = expf(rlj[k] - m0); if (k < 5) e5[k] = e; sum += e; }
  const float inv = 1.0f / sum;

  float remb[16];
  #pragma unroll
  for (int c = 0; c < 16; ++c) {
    float acc = e5[0] * embs[c];
    #pragma unroll
    for (int k = 1; k < 5; ++k) acc += e5[k] * embs[k * 16 + c];
    remb[c] = acc * inv;
  }

  float zj[32];
  #pragma unroll
  for (int c = 0; c < 32; c += 4) {
    const float4 v = *(const float4*)(z + j * 32 + c);
    zj[c] = v.x; zj[c + 1] = v.y; zj[c + 2] = v.z; zj[c + 3] = v.w;
  }

  #pragma unroll
  for (int r = 0; r < 8; ++r) {
    const int o = 4 * r + s;
    float acc = cRT1[o];
    #pragma unroll
    for (int c = 0; c < 16; ++c) acc += rt1c[o * 16 + c] * remb[c];
    tx[q * 36 + o] = siluf(acc);
  }
  __syncthreads();  // B1
  float t1[32];
  #pragma unroll
  for (int c = 0; c < 32; c += 4) {
    const float4 v = *(const float4*)(tx + q * 36 + c);
    t1[c] = v.x; t1[c + 1] = v.y; t1[c + 2] = v.z; t1[c + 3] = v.w;
  }
  float updS = bRT2[s], upd4 = bRT2[4];
  #pragma unroll
  for (int c = 0; c < 32; ++c) { updS += rt2s[s * 32 + c] * t1[c]; upd4 += rt2s[128 + c] * t1[c]; }
  float nlg[15];
  #pragma unroll
  for (int k = 0; k < 4; ++k) nlg[k] = 0.7f * rlj[k] + 0.3f * __shfl(updS, lbase + k);
  nlg[4] = 0.7f * rlj[4] + 0.3f * upd4;
  #pragma unroll
  for (int k = 5; k < 15; ++k) nlg[k] = rlj[k];

  #pragma unroll
  for (int r = 0; r < 16; ++r) {
    const int o = 4 * r + s;
    const float* wrow = d1c + o * 48;
    float acc = cD1[o];
    #pragma unroll
    for (int c = 0; c < 16; ++c) acc += wrow[c] * remb[c];
    #pragma unroll
    for (int c = 0; c < 32; ++c) acc += wrow[16 + c] * zj[c];
    x1ex[q * 68 + o] = siluf(acc);
  }
  __syncthreads();  // B2

  float acc8[8];
  #pragma unroll
  for (int r = 0; r < 8; ++r) acc8[r] = bD2[4 * r + s];
  #pragma unroll
  for (int half = 0; half < 2; ++half) {
    float xh[32];
    #pragma unroll
    for (int c = 0; c < 32; c += 4) {
      const float4 v = *(const float4*)(x1ex + q * 68 + half * 32 + c);
      xh[c] = v.x; xh[c + 1] = v.y; xh[c + 2] = v.z; xh[c + 3] = v.w;
    }
    #pragma unroll
    for (int r = 0; r < 8; ++r) {
      const int o = 4 * r + s;
      #pragma unroll
      for (int c = 0; c < 32; ++c) acc8[r] += d2s[o * 64 + half * 32 + c] * xh[c];
    }
  }
  #pragma unroll
  for (int r = 0; r < 8; ++r) tx[q * 36 + 4 * r + s] = siluf(acc8[r]);
  __syncthreads();  // B3
  float x2v[32];
  #pragma unroll
  for (int c = 0; c < 32; c += 4) {
    const float4 v = *(const float4*)(tx + q * 36 + c);
    x2v[c] = v.x; x2v[c + 1] = v.y; x2v[c + 2] = v.z; x2v[c + 3] = v.w;
  }
  float dps = bD3[s];
  #pragma unroll
  for (int c = 0; c < 32; ++c) dps += d3s[s * 32 + c] * x2v[c];
  const float dp0 = __shfl(dps, lbase), dp1 = __shfl(dps, lbase + 1);
  const float dp2 = __shfl(dps, lbase + 2), dp3 = __shfl(dps, lbase + 3);
  const float sig_h = softplusf(dp2) + 0.01f;
  const float sig_l = softplusf(dp3) + 0.01f;
  const float nh = fmaxf(rh[j] + dp0 + sig_h * eps_h[j], 0.0f);
  const float nl = fmaxf(rlo[j] + dp1 + sig_l * eps_l[j], 0.0f);

  #pragma unroll
  for (int r = 0; r < 8; ++r) {
    const int o = 4 * r + s;
    const float* gr = gcs + o * 48;
    const float* cr = ccs + o * 48;
    float ga = cG[o], caa = cC[o];
    #pragma unroll
    for (int c = 0; c < 16; ++c) { ga += gr[c] * remb[c]; caa += cr[c] * remb[c]; }
    #pragma unroll
    for (int c = 0; c < 32; ++c) { ga += gr[16 + c] * zj[c]; caa += cr[16 + c] * zj[c]; }
    const float gs = 1.0f / (1.0f + expf(-ga));
    stex[q * 52 + 2 + o] = gs * zj[o] + (1.0f - gs) * tanhf(caa);
  }

  if (s == 0) {
    stex[q * 52 + 0] = nh;
    stex[q * 52 + 1] = nl;
    #pragma unroll
    for (int k = 0; k < 15; ++k) stex[q * 52 + 34 + k] = nlg[k];
    float m1 = nlg[0];
    #pragma unroll
    for (int k = 1; k < 15; ++k) m1 = fmaxf(m1, nlg[k]);
    float sum1 = 0.0f, e5b[5];
    #pragma unroll
    for (int k = 0; k < 15; ++k) { float e = expf(nlg[k] - m1); if (k < 5) e5b[k] = e; sum1 += e; }
    float dot = 0.0f;
    #pragma unroll
    for (int k = 0; k < 5; ++k) dot += e5b[k] * scal[2 + k];
    dot /= sum1;
    const float R  = fminf(fmaxf(scal[1] * dot, 0.15f), 4.0f);
    const float zz = (obs - nh) / R;
    const float xx = scal[0] * zz;
    float lcdf;
    if (xx > -6.0f) {
      double p = 0.5 * erfc(-(double)xx * 0.7071067811865475244);
      lcdf = (float)log(p);
    } else {
      const float ix2 = 1.0f / (xx * xx);
      const float ser = 1.0f + ix2 * (-1.0f + ix2 * (3.0f + ix2 * (-15.0f + ix2 * 105.0f)));
      lcdf = -0.5f * xx * xx - logf(-xx) - 0.918938533f + logf(ser);
    }
    const float loglik = 0.693147181f - logf(R) - 0.918938533f - 0.5f * zz * zz + lcdf;
    a_out[j] = (logw[j] + loglik) * 2.8853900817779268f;  // (1/tau)*log2(e)
  }
  __syncthreads();  // B4

  // Bt2 write: thread c owns state-row c; fragment-native layout, 16B stores.
  if (t < 64) {
    const int c = t;
    const int b = c >> 4, rowc = c & 15;
    if (c < 49) {
      #pragma unroll
      for (int m = 0; m < 4; ++m) {
        bf16x8 v8;
        #pragma unroll
        for (int r = 0; r < 8; ++r) v8[r] = (short)f2bf(stex[(8 * m + r) * 52 + c]);
        *(bf16x8*)(Bt + (size_t)(((blockIdx.x * 4 + b) * 64) + m * 16 + rowc) * 8) = v8;
      }
    } else if (c == 49) {
      bf16x8 v8;
      #pragma unroll
      for (int r = 0; r < 8; ++r) v8[r] = (short)0x3F80;
      #pragma unroll
      for (int m = 0; m < 4; ++m)
        *(bf16x8*)(Bt + (size_t)(((blockIdx.x * 4 + b) * 64) + m * 16 + rowc) * 8) = v8;
    } else {
      bf16x8 v8;
      #pragma unroll
      for (int r = 0; r < 8; ++r) v8[r] = 0;
      #pragma unroll
      for (int m = 0; m < 4; ++m)
        *(bf16x8*)(Bt + (size_t)(((blockIdx.x * 4 + b) * 64) + m * 16 + rowc) * 8) = v8;
    }
  }
}

// ---------------- kernel 2: fused gumbel-softmax @ state (MFMA, reg-dbuf) ----
// 8 waves/block, wave-private 64-col sub-tiles, register double-buffer of the
// RAW u data (4+4 float4 only -> no spill), bf16 LDS tiles double-buffered,
// no barriers in K-loop. Order per step: load(next) -> MFMA(cur LDS tile) ->
// transform(next, vmcnt wait lands here) -> ds_write(next parity).
struct Quad { float4 q0, q1, q2, q3, av; };

__device__ __forceinline__ void load_tile(Quad& Q, const float* __restrict__ u,
                                          const float* __restrict__ a,
                                          int i0, int cb, int r0, int c0) {
  Q.q0 = *(const float4*)(u + (size_t)(i0 + r0 + 0)  * NP + cb + c0);
  Q.q1 = *(const float4*)(u + (size_t)(i0 + r0 + 4)  * NP + cb + c0);
  Q.q2 = *(const float4*)(u + (size_t)(i0 + r0 + 8)  * NP + cb + c0);
  Q.q3 = *(const float4*)(u + (size_t)(i0 + r0 + 12) * NP + cb + c0);
  Q.av = *(const float4*)(a + cb + c0);
}

__device__ __forceinline__ void xform4(const float4 uv, const float4 e2a, unsigned short* dst) {
  bf16x4 o;
  { const float X = fmaf(fast_log2(uv.x + 1e-10f), -0.69314718056f, 1e-10f);
    const float r = fast_rcp(X); o[0] = (short)f2bf(e2a.x * r * r); }
  { const float X = fmaf(fast_log2(uv.y + 1e-10f), -0.69314718056f, 1e-10f);
    const float r = fast_rcp(X); o[1] = (short)f2bf(e2a.y * r * r); }
  { const float X = fmaf(fast_log2(uv.z + 1e-10f), -0.69314718056f, 1e-10f);
    const float r = fast_rcp(X); o[2] = (short)f2bf(e2a.z * r * r); }
  { const float X = fmaf(fast_log2(uv.w + 1e-10f), -0.69314718056f, 1e-10f);
    const float r = fast_rcp(X); o[3] = (short)f2bf(e2a.w * r * r); }
  *(bf16x4*)dst = o;
}

__device__ __forceinline__ void xform_tile(const Quad& Q, unsigned short* tp, int r0, int c0) {
  float4 e2a;
  e2a.x = fast_exp2(Q.av.x); e2a.y = fast_exp2(Q.av.y);
  e2a.z = fast_exp2(Q.av.z); e2a.w = fast_exp2(Q.av.w);
  xform4(Q.q0, e2a, tp + (r0 + 0)  * TSTR + c0);
  xform4(Q.q1, e2a, tp + (r0 + 4)  * TSTR + c0);
  xform4(Q.q2, e2a, tp + (r0 + 8)  * TSTR + c0);
  xform4(Q.q3, e2a, tp + (r0 + 12) * TSTR + c0);
}

__device__ __forceinline__ void mfma_tile(f32x4& a0, f32x4& a1, f32x4& a2, f32x4& a3,
                                          const unsigned short* tp,
                                          const unsigned short* __restrict__ Bt,
                                          int jblk0, int l) {
  #pragma unroll
  for (int kb = 0; kb < 2; ++kb) {
    const bf16x8 af = *(const bf16x8*)(tp + (l & 15) * TSTR + (kb << 5) + ((l >> 4) << 3));
    const unsigned short* bp = Bt + (size_t)((jblk0 + kb) << 2) * 512;
    const bf16x8 b0 = *(const bf16x8*)(bp + (0 * 64 + l) * 8);
    const bf16x8 b1 = *(const bf16x8*)(bp + (1 * 64 + l) * 8);
    const bf16x8 b2 = *(const bf16x8*)(bp + (2 * 64 + l) * 8);
    const bf16x8 b3 = *(const bf16x8*)(bp + (3 * 64 + l) * 8);
    a0 = __builtin_amdgcn_mfma_f32_16x16x32_bf16(af, b0, a0, 0, 0, 0);
    a1 = __builtin_amdgcn_mfma_f32_16x16x32_bf16(af, b1, a1, 0, 0, 0);
    a2 = __builtin_amdgcn_mfma_f32_16x16x32_bf16(af, b2, a2, 0, 0, 0);
    a3 = __builtin_amdgcn_mfma_f32_16x16x32_bf16(af, b3, a3, 0, 0, 0);
  }
}

__global__ __launch_bounds__(512) void k_resample(const float* __restrict__ u,
                                                  const float* __restrict__ a,
                                                  const unsigned short* __restrict__ Bt,
                                                  float* __restrict__ out) {
  // union: bf16 tiles (8 waves x 2 x 2304B = 36864B) during K-loop; cacc (32KB) after
  __shared__ __align__(16) unsigned short tiles[8 * 2 * TILE_ELE];
  __shared__ float zrow[16];
  const int t = threadIdx.x;
  const int w = t >> 6, l = t & 63;
  const int i0 = blockIdx.x << 4;
  const int jw = w << 10;
  const int r0 = l >> 4;          // 0..3 (staging row base)
  const int c0 = (l & 15) << 2;   // 0..60 (staging col, floats)
  unsigned short* tw = tiles + w * 2 * TILE_ELE;

  f32x4 acc0 = {0.f, 0.f, 0.f, 0.f}, acc1 = acc0, acc2 = acc0, acc3 = acc0;

  Quad QA, QB;
  load_tile(QA, u, a, i0, jw, r0, c0);
  xform_tile(QA, tw, r0, c0);                       // prologue: tile 0 -> parity 0

  #pragma unroll
  for (int gp = 0; gp < 8; ++gp) {
    const int g0 = gp * 2;
    load_tile(QB, u, a, i0, jw + (g0 + 1) * 64, r0, c0);      // prefetch g0+1
    mfma_tile(acc0, acc1, acc2, acc3, tw, Bt, (jw + g0 * 64) >> 5, l);
    xform_tile(QB, tw + TILE_ELE, r0, c0);                    // -> parity 1
    if (gp < 7) load_tile(QA, u, a, i0, jw + (g0 + 2) * 64, r0, c0);  // prefetch g0+2
    mfma_tile(acc0, acc1, acc2, acc3, tw + TILE_ELE, Bt, (jw + (g0 + 1) * 64) >> 5, l);
    if (gp < 7) xform_tile(QA, tw, r0, c0);                   // -> parity 0
  }

  __syncthreads();                 // all waves done with tiles -> reuse as cacc
  float* cacc = (float*)tiles;     // [8][64][16] = 32KB <= 36864B
  float* crow = cacc + (w * 64 + l) * 16;
  #pragma unroll
  for (int r = 0; r < 4; ++r) {
    crow[0 * 4 + r] = acc0[r];
    crow[1 * 4 + r] = acc1[r];
    crow[2 * 4 + r] = acc2[r];
    crow[3 * 4 + r] = acc3[r];
  }
  __syncthreads();

  // reduce 8 K-chunks; thread t -> col c = t&63, rows ((t>>6)*2 + rr)
  const int c = t & 63;
  float v[2];
  #pragma unroll
  for (int rr = 0; rr < 2; ++rr) {
    const int r    = ((t >> 6) << 1) + rr;
    const int lsrc = ((r >> 2) << 4) | (c & 15);
    const int reg  = ((c >> 4) << 2) + (r & 3);
    float sv = 0.0f;
    #pragma unroll
    for (int ww = 0; ww < 8; ++ww) sv += cacc[(ww * 64 + lsrc) * 16 + reg];
    v[rr] = sv;
    if (c == 49) zrow[r] = sv;  // ones-column = row normalizer Z_i
  }
  __syncthreads();
  if (c < 49) {
    #pragma unroll
    for (int rr = 0; rr < 2; ++rr) {
      const int r = ((t >> 6) << 1) + rr;
      out[(size_t)(i0 + r) * 49 + c] = v[rr] / zrow[r];
    }
  }
}

extern "C" void kernel_launch(void* const* d_in, const int* in_sizes, int n_in,
                              void* d_out, int out_size, void* d_ws, size_t ws_size,
                              hipStream_t stream) {
  const float* rh    = (const float*)d_in[0];
  const float* rlo   = (const float*)d_in[1];
  const float* z     = (const float*)d_in[2];
  const float* rlog  = (const float*)d_in[3];
  const float* logw  = (const float*)d_in[4];
  const float* h_t   = (const float*)d_in[5];
  const float* obs   = (const float*)d_in[6];
  const float* eps_h = (const float*)d_in[7];
  const float* eps_l = (const float*)d_in[8];
  const float* u     = (const float*)d_in[9];
  const float* embed = (const float*)d_in[10];
  const float* W_rt1 = (const float*)d_in[11];
  const float* b_rt1 = (const float*)d_in[12];
  const float* W_rt2 = (const float*)d_in[13];
  const float* b_rt2 = (const float*)d_in[14];
  const float* W_d1  = (const float*)d_in[15];
  const float* b_d1  = (const float*)d_in[16];
  const float* W_d2  = (const float*)d_in[17];
  const float* b_d2  = (const float*)d_in[18];
  const float* W_d3  = (const float*)d_in[19];
  const float* b_d3  = (const float*)d_in[20];
  const float* W_g   = (const float*)d_in[21];
  const float* b_g   = (const float*)d_in[22];
  const float* W_c   = (const float*)d_in[23];
  const float* b_c   = (const float*)d_in[24];
  const float* log_R = (const float*)d_in[25];
  const float* log_obs_scale = (const float*)d_in[26];
  const float* W_a1  = (const float*)d_in[27];
  const float* b_a1  = (const float*)d_in[28];
  const float* W_a2  = (const float*)d_in[29];
  const float* b_a2  = (const float*)d_in[30];

  float* ws_a = (float*)((char*)d_ws + 36864);
  unsigned short* ws_bt = (unsigned short*)((char*)d_ws + 73728);

  k_particle<<<256, 128, 0, stream>>>(rh, rlo, z, rlog, logw, h_t, obs, eps_h, eps_l,
                                      embed, W_rt1, b_rt1, W_rt2, b_rt2,
                                      W_d1, b_d1, W_d2, b_d2, W_d3, b_d3,
                                      W_g, b_g, W_c, b_c, log_R, log_obs_scale,
                                      W_a1, b_a1, W_a2, b_a2, ws_a, ws_bt);
  k_resample<<<512, 512, 0, stream>>>(u, ws_a, ws_bt, (float*)d_out);
}